// Round 10
// baseline (54.141 us; speedup 1.0000x reference)
//
#include <hip/hip_runtime.h>
#include <hip/hip_cooperative_groups.h>
#include <math.h>

#define S_ 32
#define B_ 128
#define M_ 128
#define F_ 512
#define C_ 100
#define SB 16     // s-rows per block
#define RWZ 136   // f16 row stride for Zf (272 B)
#define RWP 136   // f16 row stride for Pt (272 B)

typedef _Float16 f16;
typedef _Float16 f16x4 __attribute__((ext_vector_type(4)));
typedef _Float16 f16x8 __attribute__((ext_vector_type(8)));
typedef float f32x4 __attribute__((ext_vector_type(4)));

// ws layout (bytes):
//  BTf  @ 0     : 4 kc x 7 ct x 64 lane x 16B = 28672   beta frags   [B-op, phase B]
//  EPf  @ 28672 : 4 kc x 8 mt x 64 lane x 16B = 32768   exp(+2*beta) [B-op, phase D]
//  ENf  @ 61440 : 32768                                 exp(-2*beta)
//  etag @ 94208 : f32[128][128] = 65536
#define WS_BT  0
#define WS_EP  28672
#define WS_EN  61440
#define WS_ETA 94208

namespace cg = cooperative_groups;

// Single cooperative kernel. Grid 256 = (sh 0/1) x (b 0..127), 512 thr = 8 waves.
__global__ __launch_bounds__(512) void k_all(
    const float* __restrict__ x, const int* __restrict__ y,
    const float* __restrict__ Z, const float* __restrict__ alpha0,
    const float* __restrict__ alpha, const float* __restrict__ beta0,
    const float* __restrict__ beta, char* __restrict__ ws,
    float* __restrict__ out) {
  const int gid = blockIdx.x;
  const int sh = gid >> 7;     // 0,1
  const int b = gid & 127;     // 0..127
  const int tid = threadIdx.x;
  const int lane = tid & 63;
  const int w = tid >> 6;      // 0..7
  const int l15 = lane & 15;
  const int lg = lane >> 4;    // 0..3

  __shared__ f16 Zf[SB * RWZ];       // 4352 B [p][m]
  __shared__ float baseS[SB * 112];  // 7168 B
  __shared__ f16 Pt[SB * RWP];       // 4352 B [p][c], c>=100 zeroed
  __shared__ float PybS[SB];

  // ================= pre-sync =================
  // Zf: 16 Z rows of this (sh,b) -> f16 LDS (one float4 per thread)
  {
    int p = tid >> 5, q = tid & 31;
    float4 v = ((const float4*)Z)[((size_t)(sh * SB + p) * B_ + b) * 32 + q];
    f16x4 h = {(f16)v.x, (f16)v.y, (f16)v.z, (f16)v.w};
    *(f16x4*)&Zf[p * RWZ + q * 4] = h;
  }

  // Table gen: one coalesced beta read -> 3 fragment-slot writes
  {
    const int vid = gid * 512 + tid;
    if (vid < 12800) {
      int c = vid >> 7, mm = vid & 127;
      float bv = beta[vid];
      {  // BTf: (c,m) -> frag(kc=m>>5, ct=c>>4), lane=(lg2<<4)|cl, elem ii
        int kc = mm >> 5, lg2 = (mm >> 3) & 3, ii = mm & 7;
        int ct = c >> 4, cl = c & 15;
        *(f16*)(ws + WS_BT +
                (size_t)(((kc * 7 + ct) * 64 + lg2 * 16 + cl) * 16 + ii * 2)) =
            (f16)bv;
      }
      {  // EPf/ENf: (c,m) -> frag(kc=c>>5, mt=m>>4), lane=(lg2<<4)|ml, elem ii
        int mt = mm >> 4, ml = mm & 15;
        int kc = c >> 5, lg2 = (c >> 3) & 3, ii = c & 7;
        size_t off = (size_t)(((kc * 8 + mt) * 64 + lg2 * 16 + ml) * 16 + ii * 2);
        *(f16*)(ws + WS_EP + off) = (f16)__expf(2.f * bv);
        *(f16*)(ws + WS_EN + off) = (f16)__expf(-2.f * bv);
      }
    } else if (vid < 14336) {  // BTf zero pad: c 100..111
      int rel = vid - 12800;
      int c = 100 + (rel >> 7), mm = rel & 127;
      int kc = mm >> 5, lg2 = (mm >> 3) & 3, ii = mm & 7;
      int ct = c >> 4, cl = c & 15;
      *(f16*)(ws + WS_BT +
              (size_t)(((kc * 7 + ct) * 64 + lg2 * 16 + cl) * 16 + ii * 2)) =
          (f16)0.f;
    } else if (vid < 17920) {  // EP/EN zero pad: c 100..127
      int rel = vid - 14336;
      int c = 100 + (rel >> 7), mm = rel & 127;
      int mt = mm >> 4, ml = mm & 15;
      int kc = c >> 5, lg2 = (c >> 3) & 3, ii = c & 7;
      size_t off = (size_t)(((kc * 8 + mt) * 64 + lg2 * 16 + ml) * 16 + ii * 2);
      *(f16*)(ws + WS_EP + off) = (f16)0.f;
      *(f16*)(ws + WS_EN + off) = (f16)0.f;
    }
  }

  if (sh == 0) {
    // eta row b: coalesced lanes-over-f wave-GEMV
    float* etag = (float*)(ws + WS_ETA);
    const float4* x4 = (const float4*)x;
    const float4* a4 = (const float4*)alpha;
    float4 xr[8];
#pragma unroll
    for (int r = 0; r < 8; ++r) xr[r] = x4[b * 128 + r * 16 + l15];
#pragma unroll
    for (int j = 0; j < 4; ++j) {
      int m = w * 16 + j * 4 + lg;
      float acc = 0.f;
#pragma unroll
      for (int r = 0; r < 8; ++r) {
        float4 av = a4[(size_t)m * 128 + r * 16 + l15];
        float4 xv = xr[r];
        acc = fmaf(av.x, xv.x, acc); acc = fmaf(av.y, xv.y, acc);
        acc = fmaf(av.z, xv.z, acc); acc = fmaf(av.w, xv.w, acc);
      }
      acc += __shfl_xor(acc, 1);
      acc += __shfl_xor(acc, 2);
      acc += __shfl_xor(acc, 4);
      acc += __shfl_xor(acc, 8);
      if (l15 == 0) {
        float l = alpha0[m] + acc;
        etag[b * 128 + m] = 1.f / (1.f + __expf(-l));
      }
    }
  } else {
    if (tid < M_) out[b * M_ + tid] = 0.f;
  }

  cg::this_grid().sync();

  // ================= post-sync =================
  const int yb = y[b];
  const int m = w * 16 + l15;

  // Issue-early: all fragments + epilogue scalars
  f16x8 bp[4], bn[4], bfr[4];
#pragma unroll
  for (int kc = 0; kc < 4; ++kc) {
    bp[kc] = *(const f16x8*)(ws + WS_EP + (size_t)((kc * 8 + w) * 64 + lane) * 16);
    bn[kc] = *(const f16x8*)(ws + WS_EN + (size_t)((kc * 8 + w) * 64 + lane) * 16);
    bfr[kc] = *(const f16x8*)(ws + WS_BT + (size_t)((kc * 7 + (w % 7)) * 64 + lane) * 16);
  }
  const float bym = beta[yb * M_ + m];
  const float eta_v = ((const float*)(ws + WS_ETA))[b * M_ + m];

  // ---- B: base[16 p][112 c] = Zf x beta^T (K=128) ----
  if (w < 7) {
    f32x4 acc = {0.f, 0.f, 0.f, 0.f};
    const char* ZfB = (const char*)Zf;
#pragma unroll
    for (int kc = 0; kc < 4; ++kc) {
      f16x8 a0 = *(const f16x8*)(ZfB + l15 * (RWZ * 2) + kc * 64 + lg * 16);
      acc = __builtin_amdgcn_mfma_f32_16x16x32_f16(a0, bfr[kc], acc, 0, 0, 0);
    }
    int col = w * 16 + l15;
    float b0v = (col < C_) ? beta0[col] : 0.f;
#pragma unroll
    for (int j = 0; j < 4; ++j) baseS[(lg * 4 + j) * 112 + col] = acc[j] + b0v;
  }
  __syncthreads();

  // ---- C: softmax; wave w -> rows p = 2w, 2w+1 ----
  {
#pragma unroll
    for (int k = 0; k < 2; ++k) {
      int p = w * 2 + k;
      float v1 = baseS[p * 112 + lane];
      float v2 = (lane < 36) ? baseS[p * 112 + 64 + lane] : -1e30f;
      float mx = fmaxf(v1, v2);
#pragma unroll
      for (int off = 32; off > 0; off >>= 1) mx = fmaxf(mx, __shfl_xor(mx, off));
      float e1 = __expf(v1 - mx);
      float e2 = (lane < 36) ? __expf(v2 - mx) : 0.f;
      float sm = e1 + e2;
#pragma unroll
      for (int off = 32; off > 0; off >>= 1) sm += __shfl_xor(sm, off);
      float rd = 1.f / sm;
      Pt[p * RWP + lane] = (f16)(e1 * rd);
      Pt[p * RWP + 64 + lane] = (f16)((lane < 36) ? e2 * rd : 0.f);
      if (lane == yb) PybS[p] = e1 * rd;
      if (lane + 64 == yb) PybS[p] = e2 * rd;
    }
  }
  __syncthreads();

  // ---- D: den± [16 p][128 m] = Pt x exp-tables^T (K=128) + epilogue ----
  {
    f32x4 pA = {0.f, 0.f, 0.f, 0.f}, nA = {0.f, 0.f, 0.f, 0.f};
    const char* PtB = (const char*)Pt;
#pragma unroll
    for (int kc = 0; kc < 4; ++kc) {
      f16x8 a0 = *(const f16x8*)(PtB + l15 * (RWP * 2) + kc * 64 + lg * 16);
      pA = __builtin_amdgcn_mfma_f32_16x16x32_f16(a0, bp[kc], pA, 0, 0, 0);
      nA = __builtin_amdgcn_mfma_f32_16x16x32_f16(a0, bn[kc], nA, 0, 0, 0);
    }
    float epy = __expf(2.f * bym), eny = __expf(-2.f * bym);
    float ome = 1.f - eta_v;
    float o = 0.f;
#pragma unroll
    for (int j = 0; j < 4; ++j) {
      int p = lg * 4 + j;
      float z = (float)Zf[p * RWZ + m];
      float pyb = PybS[p];
      o += (z > 0.f) ? fmaf(pyb, eta_v, (pyb * eny / nA[j]) * ome)
                     : fmaf(pyb * epy / pA[j], eta_v, pyb * ome);
    }
    o += __shfl_xor(o, 16);
    o += __shfl_xor(o, 32);
    if (lane < 16) atomicAdd(&out[b * M_ + w * 16 + l15], o);
  }
}

extern "C" void kernel_launch(void* const* d_in, const int* in_sizes, int n_in,
                              void* d_out, int out_size, void* d_ws, size_t ws_size,
                              hipStream_t stream) {
  const float* x = (const float*)d_in[0];
  const int* y = (const int*)d_in[1];
  const float* Z = (const float*)d_in[2];
  const float* alpha0 = (const float*)d_in[3];
  const float* alpha = (const float*)d_in[4];
  const float* beta0 = (const float*)d_in[5];
  const float* beta = (const float*)d_in[6];
  float* out = (float*)d_out;
  char* ws = (char*)d_ws;

  void* args[] = {(void*)&x,      (void*)&y,    (void*)&Z,
                  (void*)&alpha0, (void*)&alpha, (void*)&beta0,
                  (void*)&beta,   (void*)&ws,   (void*)&out};
  hipLaunchCooperativeKernel((const void*)k_all, dim3(256), dim3(512), args, 0,
                             stream);
}

// Round 11
// 18.714 us; speedup vs baseline: 2.8930x; 2.8930x over previous
//
#include <hip/hip_runtime.h>
#include <math.h>

#define S_ 32
#define B_ 128
#define M_ 128
#define F_ 512
#define C_ 100
#define RWZ 136   // f16 row stride for Zf (272 B)
#define RWP 136   // f16 row stride for Pt (272 B)

typedef _Float16 f16;
typedef _Float16 f16x4 __attribute__((ext_vector_type(4)));
typedef _Float16 f16x8 __attribute__((ext_vector_type(8)));
typedef float f32x4 __attribute__((ext_vector_type(4)));

// Single ordinary kernel. Grid (2 mh, 128 b), 512 thr = 8 waves.
// Each block: full 32-s pipeline for (b, m-half). All tables block-local in LDS.
__global__ __launch_bounds__(512) void k_all(
    const float* __restrict__ x, const int* __restrict__ y,
    const float* __restrict__ Z, const float* __restrict__ alpha0,
    const float* __restrict__ alpha, const float* __restrict__ beta0,
    const float* __restrict__ beta, float* __restrict__ out) {
  const int mh = blockIdx.x;   // 0,1
  const int b = blockIdx.y;    // 0..127
  const int tid = threadIdx.x;
  const int lane = tid & 63;
  const int w = tid >> 6;      // 0..7
  const int l15 = lane & 15;
  const int lg = lane >> 4;    // 0..3

  // Fragment blobs: lane-contiguous 16B slots -> conflict-free ds_read_b128
  __shared__ __align__(16) f16 BTf[4 * 7 * 64 * 8];   // 28672 B beta frags (B-op of B)
  __shared__ __align__(16) f16 EPf[4 * 4 * 64 * 8];   // 16384 B exp(+2b) m-half
  __shared__ __align__(16) f16 ENf[4 * 4 * 64 * 8];   // 16384 B exp(-2b) m-half
  __shared__ __align__(16) f16 Zf[S_ * RWZ];          // 8704 B [p][m full]
  __shared__ float baseS[S_ * 112];                   // 14336 B
  __shared__ __align__(16) f16 Pt[S_ * RWP];          // 8704 B [p][c], c>=100 zero
  __shared__ float PybS[S_];
  __shared__ float etaS[64];
  __shared__ float redS[128];

  const int yb = y[b];

  // ---- A1: stage all 32 Z rows -> f16 LDS (2 float4 per thread) ----
  {
    const float4* Z4 = (const float4*)Z;
#pragma unroll
    for (int k = 0; k < 2; ++k) {
      int i4 = tid + k * 512;  // 0..1023
      int p = i4 >> 5, q = i4 & 31;
      float4 v = Z4[((size_t)p * B_ + b) * 32 + q];
      f16x4 h = {(f16)v.x, (f16)v.y, (f16)v.z, (f16)v.w};
      *(f16x4*)&Zf[p * RWZ + q * 4] = h;
    }
  }

  // ---- A2: block-local tables (one sweep covers values AND zero-pads) ----
  for (int i = tid; i < 16384; i += 512) {  // c = i>>7 (0..127), mm = i&127
    int c = i >> 7, mm = i & 127;
    float bv = (c < C_) ? beta[i] : 0.f;    // beta idx == i for c < 100
    if (c < 112) {  // BTf frag(kc=m>>5, ct=c>>4); lane=(lg<<4)|cl; elem=m&7
      int kc = mm >> 5, lg2 = (mm >> 3) & 3, ii = mm & 7;
      int ct = c >> 4, cl = c & 15;
      BTf[((kc * 7 + ct) * 64 + lg2 * 16 + cl) * 8 + ii] = (f16)bv;
    }
    int ml = mm - mh * 64;
    if ((unsigned)ml < 64u) {  // EP/EN frag(kc=c>>5, mt=ml>>4); lane=(lg<<4)|mll
      int mt = ml >> 4, mll = ml & 15;
      int kc = c >> 5, lg2 = (c >> 3) & 3, ii = c & 7;
      int off = ((kc * 4 + mt) * 64 + lg2 * 16 + mll) * 8 + ii;
      EPf[off] = (c < C_) ? (f16)__expf(2.f * bv) : (f16)0.f;
      ENf[off] = (c < C_) ? (f16)__expf(-2.f * bv) : (f16)0.f;
    }
  }

  // ---- A3: eta for this m-half (wave w -> 8 m values) ----
  {
    const float4* x4 = (const float4*)x;
    const float4* a4 = (const float4*)alpha;
    float4 xr[8];
#pragma unroll
    for (int r = 0; r < 8; ++r) xr[r] = x4[b * 128 + r * 16 + l15];
#pragma unroll
    for (int j = 0; j < 2; ++j) {
      int ml = w * 8 + j * 4 + lg;
      int m = mh * 64 + ml;
      float acc = 0.f;
#pragma unroll
      for (int r = 0; r < 8; ++r) {
        float4 av = a4[(size_t)m * 128 + r * 16 + l15];
        float4 xv = xr[r];
        acc = fmaf(av.x, xv.x, acc); acc = fmaf(av.y, xv.y, acc);
        acc = fmaf(av.z, xv.z, acc); acc = fmaf(av.w, xv.w, acc);
      }
      acc += __shfl_xor(acc, 1);
      acc += __shfl_xor(acc, 2);
      acc += __shfl_xor(acc, 4);
      acc += __shfl_xor(acc, 8);
      if (l15 == 0) {
        float l = alpha0[m] + acc;
        etaS[ml] = 1.f / (1.f + __expf(-l));
      }
    }
  }
  __syncthreads();  // (1) Zf, tables, etaS ready

  // ---- B: base[32 p][112 c] = Zf x beta^T (K=128); wave w<7 -> c-tile w ----
  if (w < 7) {
    f32x4 acc0 = {0.f, 0.f, 0.f, 0.f}, acc1 = {0.f, 0.f, 0.f, 0.f};
#pragma unroll
    for (int kc = 0; kc < 4; ++kc) {
      f16x8 bfr = *(const f16x8*)&BTf[((kc * 7 + w) * 64 + lane) * 8];
      f16x8 a0 = *(const f16x8*)&Zf[l15 * RWZ + kc * 32 + lg * 8];
      f16x8 a1 = *(const f16x8*)&Zf[(16 + l15) * RWZ + kc * 32 + lg * 8];
      acc0 = __builtin_amdgcn_mfma_f32_16x16x32_f16(a0, bfr, acc0, 0, 0, 0);
      acc1 = __builtin_amdgcn_mfma_f32_16x16x32_f16(a1, bfr, acc1, 0, 0, 0);
    }
    int col = w * 16 + l15;
    float b0v = (col < C_) ? beta0[col] : 0.f;
#pragma unroll
    for (int j = 0; j < 4; ++j) {
      baseS[(lg * 4 + j) * 112 + col] = acc0[j] + b0v;
      baseS[(16 + lg * 4 + j) * 112 + col] = acc1[j] + b0v;
    }
  }
  __syncthreads();  // (2) base ready

  // Issue-early: phase-D B-fragments (hide LDS latency under softmax)
  const int pt = w >> 2, mt = w & 3;
  f16x8 bp[4], bn[4];
#pragma unroll
  for (int kc = 0; kc < 4; ++kc) {
    bp[kc] = *(const f16x8*)&EPf[((kc * 4 + mt) * 64 + lane) * 8];
    bn[kc] = *(const f16x8*)&ENf[((kc * 4 + mt) * 64 + lane) * 8];
  }

  // ---- C: softmax; wave w -> rows p = 4w..4w+3 ----
  {
#pragma unroll
    for (int k = 0; k < 4; ++k) {
      int p = w * 4 + k;
      float v1 = baseS[p * 112 + lane];
      float v2 = (lane < 36) ? baseS[p * 112 + 64 + lane] : -1e30f;
      float mx = fmaxf(v1, v2);
#pragma unroll
      for (int off = 32; off > 0; off >>= 1) mx = fmaxf(mx, __shfl_xor(mx, off));
      float e1 = __expf(v1 - mx);
      float e2 = (lane < 36) ? __expf(v2 - mx) : 0.f;
      float sm = e1 + e2;
#pragma unroll
      for (int off = 32; off > 0; off >>= 1) sm += __shfl_xor(sm, off);
      float rd = 1.f / sm;
      Pt[p * RWP + lane] = (f16)(e1 * rd);
      Pt[p * RWP + 64 + lane] = (f16)((lane < 36) ? e2 * rd : 0.f);
      if (lane == yb) PybS[p] = e1 * rd;
      if (lane + 64 == yb) PybS[p] = e2 * rd;
    }
  }
  __syncthreads();  // (3) Pt, PybS ready

  // ---- D: den±[32 p][64 m] = Pt x EP/EN^T (K=128); wave (pt, mt) ----
  {
    f32x4 pA = {0.f, 0.f, 0.f, 0.f}, nA = {0.f, 0.f, 0.f, 0.f};
#pragma unroll
    for (int kc = 0; kc < 4; ++kc) {
      f16x8 a0 = *(const f16x8*)&Pt[(pt * 16 + l15) * RWP + kc * 32 + lg * 8];
      pA = __builtin_amdgcn_mfma_f32_16x16x32_f16(a0, bp[kc], pA, 0, 0, 0);
      nA = __builtin_amdgcn_mfma_f32_16x16x32_f16(a0, bn[kc], nA, 0, 0, 0);
    }
    int ml = mt * 16 + l15;
    int m = mh * 64 + ml;
    float bym = beta[yb * M_ + m];
    float epy = __expf(2.f * bym), eny = __expf(-2.f * bym);
    float eta_v = etaS[ml];
    float ome = 1.f - eta_v;
    float o = 0.f;
#pragma unroll
    for (int j = 0; j < 4; ++j) {
      int p = pt * 16 + lg * 4 + j;
      float z = (float)Zf[p * RWZ + m];
      float pyb = PybS[p];
      o += (z > 0.f) ? fmaf(pyb, eta_v, (pyb * eny / nA[j]) * ome)
                     : fmaf(pyb * epy / pA[j], eta_v, pyb * ome);
    }
    o += __shfl_xor(o, 16);
    o += __shfl_xor(o, 32);
    if (lane < 16) redS[pt * 64 + mt * 16 + l15] = o;
  }
  __syncthreads();  // (4) partials ready

  if (tid < 64) out[b * M_ + mh * 64 + tid] = redS[tid] + redS[64 + tid];
}

extern "C" void kernel_launch(void* const* d_in, const int* in_sizes, int n_in,
                              void* d_out, int out_size, void* d_ws, size_t ws_size,
                              hipStream_t stream) {
  const float* x = (const float*)d_in[0];
  const int* y = (const int*)d_in[1];
  const float* Z = (const float*)d_in[2];
  const float* alpha0 = (const float*)d_in[3];
  const float* alpha = (const float*)d_in[4];
  const float* beta0 = (const float*)d_in[5];
  const float* beta = (const float*)d_in[6];
  float* out = (float*)d_out;

  k_all<<<dim3(2, B_), dim3(512), 0, stream>>>(x, y, Z, alpha0, alpha, beta0,
                                               beta, out);
}

// Round 12
// 16.179 us; speedup vs baseline: 3.3464x; 1.1567x over previous
//
#include <hip/hip_runtime.h>
#include <math.h>

#define S_ 32
#define B_ 128
#define M_ 128
#define F_ 512
#define C_ 100

typedef _Float16 f16;
typedef _Float16 f16x8 __attribute__((ext_vector_type(8)));
typedef float f32x4 __attribute__((ext_vector_type(4)));

// One ordinary kernel. Grid (2 mh, 128 b), 512 thr = 8 waves.
// All MFMA operands in fragment-blob LDS (conflict-free b128) or registers.
// B-operands built in-register from global beta (no shared tables, no ws).
__global__ __launch_bounds__(512) void k_all(
    const float* __restrict__ x, const int* __restrict__ y,
    const float* __restrict__ Z, const float* __restrict__ alpha0,
    const float* __restrict__ alpha, const float* __restrict__ beta0,
    const float* __restrict__ beta, float* __restrict__ out) {
  const int mh = blockIdx.x;   // 0,1
  const int b = blockIdx.y;    // 0..127
  const int tid = threadIdx.x;
  const int lane = tid & 63;
  const int w = tid >> 6;      // 0..7
  const int l15 = lane & 15;
  const int lg = lane >> 4;    // 0..3

  // Fragment blobs: slot = frag_id*64 + lane, 8 f16 (16 B) per slot.
  __shared__ __align__(16) f16 ZAf[512 * 8];   // 8 KB: Z frags (kc,rt): A-op of B; sign source
  __shared__ __align__(16) f16 PtAf[512 * 8];  // 8 KB: P frags (kc,pt): A-op of D
  __shared__ float baseS[S_ * 112];            // 14 KB
  __shared__ float PybS[S_];
  __shared__ float etaS[64];
  __shared__ float redS[128];

  const int yb = y[b];

  // ---- A1: Z -> ZAf fragment slots (thread == slot; conflict-free write) ----
  // slot s: kc=s>>7, rt=(s>>6)&1, lane bits (lg2=(s>>4)&3, l15s=s&15)
  // holds Z[p=rt*16+l15s][m = kc*32+lg2*8 + 0..7]
  {
    int s = tid;
    int kcs = s >> 7, rts = (s >> 6) & 1;
    int lgs = (s >> 4) & 3, l15s = s & 15;
    int p = rts * 16 + l15s;
    int m0 = kcs * 32 + lgs * 8;
    const float* zrow = Z + ((size_t)p * B_ + b) * M_ + m0;
    float4 u0 = *(const float4*)zrow;
    float4 u1 = *(const float4*)(zrow + 4);
    f16x8 hv = {(f16)u0.x, (f16)u0.y, (f16)u0.z, (f16)u0.w,
                (f16)u1.x, (f16)u1.y, (f16)u1.z, (f16)u1.w};
    *(f16x8*)&ZAf[s * 8] = hv;
  }

  // ---- A2: eta for this m-half (wave w -> 8 m values) ----
  {
    const float4* x4 = (const float4*)x;
    const float4* a4 = (const float4*)alpha;
    float4 xr[8];
#pragma unroll
    for (int r = 0; r < 8; ++r) xr[r] = x4[b * 128 + r * 16 + l15];
#pragma unroll
    for (int j = 0; j < 2; ++j) {
      int ml = w * 8 + j * 4 + lg;
      int m = mh * 64 + ml;
      float acc = 0.f;
#pragma unroll
      for (int r = 0; r < 8; ++r) {
        float4 av = a4[(size_t)m * 128 + r * 16 + l15];
        float4 xv = xr[r];
        acc = fmaf(av.x, xv.x, acc); acc = fmaf(av.y, xv.y, acc);
        acc = fmaf(av.z, xv.z, acc); acc = fmaf(av.w, xv.w, acc);
      }
      acc += __shfl_xor(acc, 1);
      acc += __shfl_xor(acc, 2);
      acc += __shfl_xor(acc, 4);
      acc += __shfl_xor(acc, 8);
      if (l15 == 0) {
        float l = alpha0[m] + acc;
        etaS[ml] = 1.f / (1.f + __expf(-l));
      }
    }
  }

  // ---- A3: phase-B B-frags from global beta (coalesced float4 + cvt) ----
  const int colB = w * 16 + l15;  // c column; waves 0..6 used
  f16x8 bfr[4];
  if (w < 7) {
    const float* brow = beta + (size_t)((colB < C_) ? colB : C_ - 1) * M_;
    bool ok = colB < C_;
#pragma unroll
    for (int kc = 0; kc < 4; ++kc) {
      int m0 = kc * 32 + lg * 8;
      float4 u0 = *(const float4*)(brow + m0);
      float4 u1 = *(const float4*)(brow + m0 + 4);
      if (!ok) { u0 = make_float4(0,0,0,0); u1 = make_float4(0,0,0,0); }
      bfr[kc] = (f16x8){(f16)u0.x, (f16)u0.y, (f16)u0.z, (f16)u0.w,
                        (f16)u1.x, (f16)u1.y, (f16)u1.z, (f16)u1.w};
    }
  }

  // ---- A4: phase-D B-frags: exp(+/-2*beta[c][m]) in-register ----
  const int pt = w >> 2, mt = w & 3;
  const int mD = mh * 64 + mt * 16 + l15;  // this lane's m (n-index of D)
  f16x8 bp[4], bn[4];
  {
    const float* bcol = beta + mD;
#pragma unroll
    for (int kc = 0; kc < 4; ++kc) {
      f16x8 ep, en;
#pragma unroll
      for (int ii = 0; ii < 8; ++ii) {
        int c = kc * 32 + lg * 8 + ii;
        int cs = (c < C_) ? c : C_ - 1;   // clamped; P=0 there anyway
        float bv = bcol[(size_t)cs * M_];
        float e = __expf(2.f * bv);
        ep[ii] = (f16)e;
        en[ii] = (f16)(1.f / e);
      }
      bp[kc] = ep;
      bn[kc] = en;
    }
  }
  __syncthreads();  // (1) ZAf, etaS ready

  // ---- B: base[32 p][112 c] = Z x beta^T (K=128); A from ZAf (b128, cf) ----
  if (w < 7) {
    f32x4 acc0 = {0.f, 0.f, 0.f, 0.f}, acc1 = {0.f, 0.f, 0.f, 0.f};
#pragma unroll
    for (int kc = 0; kc < 4; ++kc) {
      f16x8 a0 = *(const f16x8*)&ZAf[((kc * 2 + 0) * 64 + lane) * 8];
      f16x8 a1 = *(const f16x8*)&ZAf[((kc * 2 + 1) * 64 + lane) * 8];
      acc0 = __builtin_amdgcn_mfma_f32_16x16x32_f16(a0, bfr[kc], acc0, 0, 0, 0);
      acc1 = __builtin_amdgcn_mfma_f32_16x16x32_f16(a1, bfr[kc], acc1, 0, 0, 0);
    }
    float b0v = (colB < C_) ? beta0[colB] : 0.f;
#pragma unroll
    for (int j = 0; j < 4; ++j) {
      baseS[(lg * 4 + j) * 112 + colB] = acc0[j] + b0v;
      baseS[(16 + lg * 4 + j) * 112 + colB] = acc1[j] + b0v;
    }
  }
  __syncthreads();  // (2) base ready

  // ---- C: softmax; wave w -> rows p = 4w..4w+3; write PtAf frag slots ----
  {
#pragma unroll
    for (int k = 0; k < 4; ++k) {
      int p = w * 4 + k;
      float v1 = baseS[p * 112 + lane];
      float v2 = (lane < 36) ? baseS[p * 112 + 64 + lane] : -1e30f;
      float mx = fmaxf(v1, v2);
#pragma unroll
      for (int off = 32; off > 0; off >>= 1) mx = fmaxf(mx, __shfl_xor(mx, off));
      float e1 = __expf(v1 - mx);
      float e2 = (lane < 36) ? __expf(v2 - mx) : 0.f;
      float sm = e1 + e2;
#pragma unroll
      for (int off = 32; off > 0; off >>= 1) sm += __shfl_xor(sm, off);
      float rd = 1.f / sm;
      float p1 = e1 * rd;
      float p2 = (lane < 36) ? e2 * rd : 0.f;
      int ptp = p >> 4, l15p = p & 15;
      {  // c = lane
        int c = lane, kc = c >> 5, lg2 = (c >> 3) & 3, ii = c & 7;
        PtAf[((kc * 2 + ptp) * 64 + lg2 * 16 + l15p) * 8 + ii] = (f16)p1;
      }
      {  // c = lane + 64 (includes zero pad to 127)
        int c = lane + 64, kc = c >> 5, lg2 = (c >> 3) & 3, ii = c & 7;
        PtAf[((kc * 2 + ptp) * 64 + lg2 * 16 + l15p) * 8 + ii] = (f16)p2;
      }
      if (lane == yb) PybS[p] = p1;
      if (lane + 64 == yb) PybS[p] = p2;
    }
  }
  __syncthreads();  // (3) PtAf, PybS ready

  // ---- D: den+/-[32 p][64 m] = P x exp^T (K=128); wave (pt, mt) + epilogue ----
  {
    f32x4 pA = {0.f, 0.f, 0.f, 0.f}, nA = {0.f, 0.f, 0.f, 0.f};
#pragma unroll
    for (int kc = 0; kc < 4; ++kc) {
      f16x8 a0 = *(const f16x8*)&PtAf[((kc * 2 + pt) * 64 + lane) * 8];
      pA = __builtin_amdgcn_mfma_f32_16x16x32_f16(a0, bp[kc], pA, 0, 0, 0);
      nA = __builtin_amdgcn_mfma_f32_16x16x32_f16(a0, bn[kc], nA, 0, 0, 0);
    }
    int m = mD;
    float bym = beta[yb * M_ + m];
    float epy = __expf(2.f * bym), eny = 1.f / epy;
    float eta_v = etaS[mt * 16 + l15];
    float ome = 1.f - eta_v;
    float o = 0.f;
    int kcz = m >> 5, lgz = (m >> 3) & 3, iiz = m & 7;
#pragma unroll
    for (int j = 0; j < 4; ++j) {
      int p = pt * 16 + lg * 4 + j;
      float z = (float)ZAf[((kcz * 2 + (p >> 4)) * 64 + lgz * 16 + (p & 15)) * 8 + iiz];
      float pyb = PybS[p];
      o += (z > 0.f) ? fmaf(pyb, eta_v, (pyb * eny / nA[j]) * ome)
                     : fmaf(pyb * epy / pA[j], eta_v, pyb * ome);
    }
    o += __shfl_xor(o, 16);
    o += __shfl_xor(o, 32);
    if (lane < 16) redS[pt * 64 + mt * 16 + l15] = o;
  }
  __syncthreads();  // (4)

  if (tid < 64) out[b * M_ + mh * 64 + tid] = redS[tid] + redS[64 + tid];
}

extern "C" void kernel_launch(void* const* d_in, const int* in_sizes, int n_in,
                              void* d_out, int out_size, void* d_ws, size_t ws_size,
                              hipStream_t stream) {
  const float* x = (const float*)d_in[0];
  const int* y = (const int*)d_in[1];
  const float* Z = (const float*)d_in[2];
  const float* alpha0 = (const float*)d_in[3];
  const float* alpha = (const float*)d_in[4];
  const float* beta0 = (const float*)d_in[5];
  const float* beta = (const float*)d_in[6];
  float* out = (float*)d_out;

  k_all<<<dim3(2, B_), dim3(512), 0, stream>>>(x, y, Z, alpha0, alpha, beta0,
                                               beta, out);
}